// Round 5
// baseline (3057.453 us; speedup 1.0000x reference)
//
#include <hip/hip_runtime.h>
#include <hip/hip_bf16.h>
#include <float.h>

typedef unsigned long long u64;

// ---------- exact-rounding helpers (match numpy fp32, no FMA contraction) ----------
static __device__ __forceinline__ float d2_rn(float ax, float ay, float az,
                                              float bx, float by, float bz) {
  float dx = __fsub_rn(ax, bx), dy = __fsub_rn(ay, by), dz = __fsub_rn(az, bz);
  return __fadd_rn(__fadd_rn(__fmul_rn(dx, dx), __fmul_rn(dy, dy)), __fmul_rn(dz, dz));
}

// merge two descending-sorted top-2 lists of packed keys -> top-2 in (a1,a2)
static __device__ __forceinline__ void merge2(u64& a1, u64& a2, u64 b1, u64 b2) {
  bool agt = a1 > b1;
  u64 m1 = agt ? a1 : b1;
  u64 lo = agt ? b1 : a1;
  u64 cs = agt ? a2 : b2;
  a1 = m1;
  a2 = lo > cs ? lo : cs;
}

static __device__ __forceinline__ u64 pack_key(float v, int i) {
  // nonneg float bits are monotone as uint; ~i gives first-index tie-break under max.
  // Real keys are always > 0 (low word ~i != 0 for i < 2^31), so 0 acts as -inf.
  if (v < 0.f) return 0ull;
  return ((u64)__float_as_uint(v) << 32) | (unsigned)(~i);
}

// DPP cross-lane move of a u64 (two 32-bit halves). bound_ctrl=1 -> invalid lanes read 0.
template<int CTRL>
static __device__ __forceinline__ u64 dpp_u64(u64 x) {
  unsigned lo = (unsigned)__builtin_amdgcn_update_dpp(0, (int)(unsigned)x, CTRL, 0xF, 0xF, true);
  unsigned hi = (unsigned)__builtin_amdgcn_update_dpp(0, (int)(unsigned)(x >> 32), CTRL, 0xF, 0xF, true);
  return ((u64)hi << 32) | lo;
}

template<int CTRL>
static __device__ __forceinline__ void merge_dpp(u64& a1, u64& a2) {
  u64 b1 = dpp_u64<CTRL>(a1);
  u64 b2 = dpp_u64<CTRL>(a2);
  merge2(a1, a2, b1, b2);
}

// Full-wave top-2 reduce at VALU latency; exact result lands in LANE 63.
static __device__ __forceinline__ void wave_top2_dpp(u64& a1, u64& a2) {
  merge_dpp<0xB1>(a1, a2);    // xor 1
  merge_dpp<0x4E>(a1, a2);    // xor 2
  merge_dpp<0x141>(a1, a2);   // row_half_mirror: xor 4
  merge_dpp<0x140>(a1, a2);   // row_mirror: xor 8
  merge_dpp<0x142>(a1, a2);   // row_bcast15
  merge_dpp<0x143>(a1, a2);   // row_bcast31; lane63 = full wave
}

// max of u64 keys over each 8-lane group (valid in all lanes of the group)
static __device__ __forceinline__ u64 max8_dpp(u64 k) {
  u64 o = dpp_u64<0xB1>(k);  if (o > k) k = o;
  o = dpp_u64<0x4E>(k);      if (o > k) k = o;
  o = dpp_u64<0x141>(k);     if (o > k) k = o;
  return k;
}

#define FPS_UPDATE(PP)                                                                 \
  { _Pragma("unroll")                                                                  \
    for (int k = 0; k < NPT; ++k) {                                                    \
      float m = md[k];                                                                 \
      _Pragma("unroll")                                                                \
      for (int mm = 0; mm < (PP); ++mm)                                                \
        m = fminf(m, d2_rn(px[k], py[k], pz[k], ax[mm], ay[mm], az[mm]));              \
      md[k] = m; int j = tid + k * T;                                                  \
      if (m > v2) { if (m > v1) { v2=v1; i2=i1; v1=m; i1=j; } else { v2=m; i2=j; } }   \
    } }

// ------ FPS: T=256 (1 wave/SIMD), pool = 4 waves x top-2, accept up to 4/round ------
template<int N, int M, int NPT, int T>
static __device__ void fps_body(const float* __restrict__ P, float* __restrict__ O,
                                char* smem) {
  constexpr int W = T / 64;        // 4 waves
  constexpr int POOL = 2 * W;      // 8 pool candidates
  static_assert(N == T * NPT, "layout");
  float* xs = (float*)smem;
  float* ys = xs + N;
  float* zs = ys + N;
  uint4* slots = (uint4*)(zs + N);   // [2][W]: (k1.lo,k1.hi,k2.lo,k2.hi)
  const int tid = threadIdx.x;
  const int lane = tid & 63, wv = tid >> 6;

  for (int j = tid; j < N; j += T) {
    xs[j] = P[3 * j]; ys[j] = P[3 * j + 1]; zs[j] = P[3 * j + 2];
  }
  __syncthreads();

  const float c0x = xs[0], c0y = ys[0], c0z = zs[0];
  if (tid == 0) { O[0] = c0x; O[1] = c0y; O[2] = c0z; }

  float md[NPT], px[NPT], py[NPT], pz[NPT];
  float v1 = -1.f, v2 = -1.f; int i1 = 0, i2 = 0;
  #pragma unroll
  for (int k = 0; k < NPT; ++k) {
    int j = tid + k * T;  // ascending j -> '>' keeps first index on ties
    px[k] = xs[j]; py[k] = ys[j]; pz[k] = zs[j];
    float m = d2_rn(px[k], py[k], pz[k], c0x, c0y, c0z);
    md[k] = m;
    if (m > v2) { if (m > v1) { v2=v1; i2=i1; v1=m; i1=j; } else { v2=m; i2=j; } }
  }

  u64 a1 = pack_key(v1, i1), a2 = pack_key(v2, i2);
  wave_top2_dpp(a1, a2);
  if (lane == 63)
    slots[wv] = make_uint4((unsigned)a1, (unsigned)(a1 >> 32),
                           (unsigned)a2, (unsigned)(a2 >> 32));

  int t = 1, phase = 0;
  while (t < M) {
    __syncthreads();
    // ---- pool load: lanes 0..POOL-1 own candidate (wave=lane>>1, rank=lane&1) ----
    u64 key = 0;
    float kx = 0.f, ky = 0.f, kz = 0.f;
    if (lane < POOL) {
      uint4 s = slots[phase * W + (lane >> 1)];
      key = (lane & 1) ? (((u64)s.w << 32) | s.z) : (((u64)s.y << 32) | s.x);
      int idx = (int)(~(unsigned)key);
      kx = xs[idx]; ky = ys[idx]; kz = zs[idx];
    }
    // ---- iterative extraction with exact prefix acceptance (uniform results) ----
    float ax[4], ay[4], az[4];
    int p = 0;
    {
      unsigned usedWaves = 0;
      const int room = (M - t) < 4 ? (M - t) : 4;
      bool stop = false;
      #pragma unroll
      for (int e = 0; e < 4; ++e) {
        if (!stop && p < room) {
          u64 g = max8_dpp(key);
          u64 ball = __ballot(lane < POOL && key != 0 && key == g);
          if (ball == 0) { stop = true; }
          else {
            int s = __ffsll(ball) - 1;
            float vk = __uint_as_float((unsigned)__builtin_amdgcn_readlane((int)(unsigned)(key >> 32), s));
            float cx = __int_as_float(__builtin_amdgcn_readlane(__float_as_int(kx), s));
            float cy = __int_as_float(__builtin_amdgcn_readlane(__float_as_int(ky), s));
            float cz = __int_as_float(__builtin_amdgcn_readlane(__float_as_int(kz), s));
            bool ok = true;
            #pragma unroll
            for (int mm = 0; mm < 3; ++mm)
              if (mm < p) ok = ok && (d2_rn(cx, cy, cz, ax[mm], ay[mm], az[mm]) >= vk);
            if (!ok) { stop = true; }
            else {
              ax[p] = cx; ay[p] = cy; az[p] = cz; ++p;
              if (lane == s) key = 0;
              unsigned wbit = 1u << (s >> 1);
              if (usedWaves & wbit) stop = true;  // wave's stored top-2 exhausted
              usedWaves |= wbit;
            }
          }
        }
      }
    }
    if (tid == 0) {
      #pragma unroll
      for (int mm = 0; mm < 4; ++mm)
        if (mm < p) {
          O[3 * (t + mm)] = ax[mm]; O[3 * (t + mm) + 1] = ay[mm]; O[3 * (t + mm) + 2] = az[mm];
        }
    }
    // ---- min-update over accepted points + per-thread exact top-2 ----
    v1 = -1.f; v2 = -1.f; i1 = 0; i2 = 0;
    switch (p) {
      case 1:  FPS_UPDATE(1); break;
      case 2:  FPS_UPDATE(2); break;
      case 3:  FPS_UPDATE(3); break;
      default: FPS_UPDATE(4); break;
    }

    a1 = pack_key(v1, i1); a2 = pack_key(v2, i2);
    wave_top2_dpp(a1, a2);
    if (lane == 63)
      slots[(phase ^ 1) * W + wv] = make_uint4((unsigned)a1, (unsigned)(a1 >> 32),
                                               (unsigned)a2, (unsigned)(a2 >> 32));
    phase ^= 1;
    t += p;
  }
}

template<int N, int M, int NPT>
__global__ __launch_bounds__(256) void fps_kernel(const float* __restrict__ pos,
                                                  float* __restrict__ out) {
  __shared__ __align__(16) char smem[3 * N * 4 + 2 * 4 * 16];
  fps_body<N, M, NPT, 256>(pos + (size_t)blockIdx.x * N * 3,
                           out + (size_t)blockIdx.x * M * 3, smem);
}

// ------------- per-source g[j] = x_j @ W1x + pos_j @ W1p  (tiny GEMM) -------------
template<int C, int H>
__global__ void g_kernel(const float* __restrict__ x, const float* __restrict__ pos,
                         const float* __restrict__ W, float* __restrict__ g, int rows) {
  int idx = blockIdx.x * 256 + threadIdx.x;
  if (idx >= rows * H) return;
  int row = idx / H, h = idx - row * H;
  const float* xr = x + (size_t)row * C;
  const float* pr = pos + (size_t)row * 3;
  float acc = 0.f;
  for (int c = 0; c < C; ++c) acc = fmaf(xr[c], W[c * H + h], acc);
  #pragma unroll
  for (int c = 0; c < 3; ++c) acc = fmaf(pr[c], W[(C + c) * H + h], acc);
  g[idx] = acc;
}

// ---------------- SA layer: ball-query top-64 + MLP + max aggregation ----------------
template<int N, int H, int C, int QB>
__global__ __launch_bounds__(256) void sa_kernel(
    const float* __restrict__ src,   // [B,N,3]
    const float* __restrict__ g,     // [B,N,H]
    const float* __restrict__ qpos,  // [B,M,3]
    const float* __restrict__ W2,    // [H,C]
    const float* __restrict__ b1v,   // [H]
    const float* __restrict__ W1p,   // rows C..C+2 of W1, i.e. [3,H]
    const float* __restrict__ b2v,   // [C]
    float r2, int M,
    float* __restrict__ out)         // [B,M,C]
{
  constexpr int TPS = C / 2;       // threads per subgroup (2 channels each)
  constexpr int SG  = 256 / TPS;   // subgroups = 512 / C
  constexpr int JT  = SG * 4;      // neighbors per tile
  constexpr int STRIDE = JT + 4;
  const int tid = threadIdx.x;
  const int b = blockIdx.y;
  const int sgi = tid / TPS;
  const int c2 = 2 * (tid - sgi * TPS);

  __shared__ __align__(16) __hip_bfloat16 sW2h[H * C];
  __shared__ float sD2[N];
  __shared__ float sT[H];
  __shared__ __align__(16) float sHj[STRIDE * H];
  __shared__ float sScr[512];   // aliased scratch: hist | candidates | final reduce
  __shared__ int   sNbr[64];
  __shared__ int   sWS[4];
  __shared__ int   sCnt, sNn, sNc, sBin, sBefore;
  __shared__ float sTauV; __shared__ int sTauI;

  int*   sHist  = (int*)sScr;          // [0,256)
  float* sCand  = sScr + 256;          // [256,320)
  int*   sCandI = (int*)(sScr + 320);  // [320,384)
  float* sRed   = sScr;                // [0,512) (MLP phase only)

  const float* srcb = src + (size_t)b * N * 3;
  const float* gb   = g   + (size_t)b * N * H;

  for (int e = tid; e < H * C; e += 256) sW2h[e] = __float2bfloat16(W2[e]);

  for (int qi = 0; qi < QB; ++qi) {
    const int i = blockIdx.x * QB + qi;
    const float* qp = qpos + ((size_t)b * M + i) * 3;
    const float qx = qp[0], qy = qp[1], qz = qp[2];
    const float qq = __fadd_rn(__fadd_rn(__fmul_rn(qx, qx), __fmul_rn(qy, qy)),
                               __fmul_rn(qz, qz));
    if (tid < H)
      sT[tid] = fmaf(qx, W1p[tid], fmaf(qy, W1p[H + tid], fmaf(qz, W1p[2 * H + tid], -b1v[tid])));
    if (tid == 0) { sCnt = 0; sNn = 0; sNc = 0; }
    sHist[tid] = 0;
    __syncthreads();

    // ---- pass 1: d2 (reference formula, exact rounding) + in-radius count ----
    int lc = 0;
    for (int j = tid; j < N; j += 256) {
      float sx = srcb[3 * j], sy = srcb[3 * j + 1], sz = srcb[3 * j + 2];
      float ss  = __fadd_rn(__fadd_rn(__fmul_rn(sx, sx), __fmul_rn(sy, sy)), __fmul_rn(sz, sz));
      float dot = __fadd_rn(__fadd_rn(__fmul_rn(qx, sx), __fmul_rn(qy, sy)), __fmul_rn(qz, sz));
      float d2  = __fsub_rn(__fadd_rn(qq, ss), __fmul_rn(2.0f, dot));
      sD2[j] = d2;
      lc += (d2 <= r2) ? 1 : 0;
    }
    #pragma unroll
    for (int off = 32; off > 0; off >>= 1) lc += __shfl_xor(lc, off, 64);
    if ((tid & 63) == 0) atomicAdd(&sCnt, lc);
    __syncthreads();
    const int cnt = sCnt;

    // ---- exact rank-64 threshold (lexicographic (d2, idx), matches lax.top_k) ----
    float tauv; int taui;
    if (cnt <= 64) {
      tauv = r2; taui = 0x7fffffff;
    } else {
      const float scale = 256.0f / r2;
      for (int j = tid; j < N; j += 256) {
        float d2 = sD2[j];
        if (d2 <= r2) {
          int bin = (int)(d2 * scale);
          bin = bin < 0 ? 0 : (bin > 255 ? 255 : bin);
          atomicAdd(&sHist[bin], 1);
        }
      }
      __syncthreads();
      int cbin = sHist[tid];
      int lane = tid & 63, wvi = tid >> 6;
      int v = cbin;
      #pragma unroll
      for (int off = 1; off < 64; off <<= 1) {
        int o = __shfl_up(v, off, 64);
        if (lane >= off) v += o;
      }
      if (lane == 63) sWS[wvi] = v;
      __syncthreads();
      int wadd = 0;
      for (int w = 0; w < wvi; ++w) wadd += sWS[w];
      int incl = v + wadd, excl = incl - cbin;
      if (excl < 64 && incl >= 64) { sBin = tid; sBefore = excl; }
      __syncthreads();
      const int bstar = sBin;
      const int kneed = 64 - sBefore;
      for (int j = tid; j < N; j += 256) {
        float d2 = sD2[j];
        if (d2 <= r2) {
          int bin = (int)(d2 * scale);
          bin = bin < 0 ? 0 : (bin > 255 ? 255 : bin);
          if (bin == bstar) {
            int p = atomicAdd(&sNc, 1);
            if (p < 64) { sCand[p] = d2; sCandI[p] = j; }
          }
        }
      }
      __syncthreads();
      if (tid == 0) {
        int nc = sNc < 64 ? sNc : 64;
        for (int a = 1; a < nc; ++a) {
          float dv = sCand[a]; int di = sCandI[a];
          int p = a - 1;
          while (p >= 0 && (sCand[p] > dv || (sCand[p] == dv && sCandI[p] > di))) {
            sCand[p + 1] = sCand[p]; sCandI[p + 1] = sCandI[p]; --p;
          }
          sCand[p + 1] = dv; sCandI[p + 1] = di;
        }
        int kk = (kneed < nc ? kneed : nc) - 1; if (kk < 0) kk = 0;
        sTauV = sCand[kk]; sTauI = sCandI[kk];
      }
      __syncthreads();
      tauv = sTauV; taui = sTauI;
    }

    // ---- compact neighbor list (set membership only; order irrelevant for max) ----
    for (int j = tid; j < N; j += 256) {
      float d2 = sD2[j];
      if (d2 < tauv || (d2 == tauv && j <= taui)) {
        int p = atomicAdd(&sNn, 1);
        if (p < 64) sNbr[p] = j;
      }
    }
    __syncthreads();
    const int nn = sNn < 64 ? sNn : 64;

    // ---- MLP: h = ReLU(g[j]-t[i]);  out_c = max_j (h @ W2)_c + b2_c ----
    float m0 = -FLT_MAX, m1 = -FLT_MAX;
    for (int t0 = 0; t0 < nn; t0 += JT) {
      int jt = nn - t0; if (jt > JT) jt = JT;
      __syncthreads();
      for (int e = tid; e < JT * H; e += 256) {
        int jj = e / H, h = e - jj * H;
        float hv = 0.f;
        if (jj < jt) {
          int j = sNbr[t0 + jj];
          hv = gb[(size_t)j * H + h] - sT[h];
          hv = hv > 0.f ? hv : 0.f;
        }
        sHj[h * STRIDE + jj] = hv;
      }
      __syncthreads();
      float a0 = 0, a1 = 0, a2 = 0, a3 = 0, c0 = 0, c1 = 0, c2a = 0, c3 = 0;
      const int jbase = sgi * 4;
      for (int h = 0; h < H; ++h) {
        float4 hv = *reinterpret_cast<const float4*>(&sHj[h * STRIDE + jbase]);
        __hip_bfloat162 wp = *reinterpret_cast<const __hip_bfloat162*>(&sW2h[h * C + c2]);
        float wx = __bfloat162float(wp.x), wy = __bfloat162float(wp.y);
        a0 = fmaf(hv.x, wx, a0); a1 = fmaf(hv.y, wx, a1);
        a2 = fmaf(hv.z, wx, a2); a3 = fmaf(hv.w, wx, a3);
        c0 = fmaf(hv.x, wy, c0); c1 = fmaf(hv.y, wy, c1);
        c2a = fmaf(hv.z, wy, c2a); c3 = fmaf(hv.w, wy, c3);
      }
      if (jbase + 0 < jt) { m0 = fmaxf(m0, a0); m1 = fmaxf(m1, c0); }
      if (jbase + 1 < jt) { m0 = fmaxf(m0, a1); m1 = fmaxf(m1, c1); }
      if (jbase + 2 < jt) { m0 = fmaxf(m0, a2); m1 = fmaxf(m1, c2a); }
      if (jbase + 3 < jt) { m0 = fmaxf(m0, a3); m1 = fmaxf(m1, c3); }
    }
    __syncthreads();
    sRed[sgi * C + c2]     = m0;
    sRed[sgi * C + c2 + 1] = m1;
    __syncthreads();
    if (tid < TPS) {
      int c = 2 * tid;
      float M0 = sRed[c], M1 = sRed[c + 1];
      #pragma unroll
      for (int s2 = 1; s2 < SG; ++s2) {
        M0 = fmaxf(M0, sRed[s2 * C + c]);
        M1 = fmaxf(M1, sRed[s2 * C + c + 1]);
      }
      float o0 = nn > 0 ? M0 + b2v[c]     : 0.f;
      float o1 = nn > 0 ? M1 + b2v[c + 1] : 0.f;
      float* orow = out + (((size_t)b * M) + i) * C;
      orow[c] = o0; orow[c + 1] = o1;
    }
    __syncthreads();
  }
}

// ---------------- tail: copy p3 and synthesize batch ids into d_out ----------------
__global__ void tail_kernel(const float* __restrict__ p3, float* __restrict__ d_out) {
  int i = blockIdx.x * 256 + threadIdx.x;
  if (i < 8 * 512 * 3) d_out[524288 + i] = p3[i];
  if (i < 8 * 512)     d_out[536576 + i] = (float)(i >> 9);
}

extern "C" void kernel_launch(void* const* d_in, const int* in_sizes, int n_in,
                              void* d_out, int out_size, void* d_ws, size_t ws_size,
                              hipStream_t stream) {
  (void)in_sizes; (void)n_in; (void)out_size; (void)ws_size;
  const float* pos = (const float*)d_in[0];
  const float* w11 = (const float*)d_in[2];
  const float* b11 = (const float*)d_in[3];
  const float* w12 = (const float*)d_in[4];
  const float* b12 = (const float*)d_in[5];
  const float* w21 = (const float*)d_in[6];
  const float* b21 = (const float*)d_in[7];
  const float* w22 = (const float*)d_in[8];
  const float* b22 = (const float*)d_in[9];
  const float* w31 = (const float*)d_in[10];
  const float* b31 = (const float*)d_in[11];
  const float* w32 = (const float*)d_in[12];
  const float* b32 = (const float*)d_in[13];

  float* ws = (float*)d_ws;
  float* p1 = ws; ws += 8 * 2048 * 3;
  float* p2 = ws; ws += 8 * 512 * 3;
  float* p3 = ws; ws += 8 * 512 * 3;
  float* g1 = ws; ws += 8 * 4096 * 32;
  float* x1 = ws; ws += 8 * 2048 * 32;
  float* g2 = ws; ws += 8 * 2048 * 64;
  float* x2 = ws; ws += 8 * 512 * 64;
  float* g3 = ws; ws += 8 * 512 * 128;
  float* x3 = (float*)d_out;

  // ---------------- layer 1 ----------------
  fps_kernel<4096, 2048, 16><<<dim3(8), dim3(256), 0, stream>>>(pos, p1);
  g_kernel<3, 32><<<dim3(8 * 4096 * 32 / 256), dim3(256), 0, stream>>>(pos, pos, w11, g1, 8 * 4096);
  sa_kernel<4096, 32, 32, 8><<<dim3(2048 / 8, 8), dim3(256), 0, stream>>>(
      pos, g1, p1, w12, b11, w11 + 3 * 32, b12, 0.04f, 2048, x1);
  // ---------------- layer 2 ----------------
  fps_kernel<2048, 512, 8><<<dim3(8), dim3(256), 0, stream>>>(p1, p2);
  g_kernel<32, 64><<<dim3(8 * 2048 * 64 / 256), dim3(256), 0, stream>>>(x1, p1, w21, g2, 8 * 2048);
  sa_kernel<2048, 64, 64, 8><<<dim3(512 / 8, 8), dim3(256), 0, stream>>>(
      p1, g2, p2, w22, b21, w21 + 32 * 64, b22, 0.16f, 512, x2);
  // ---------------- layer 3 ----------------
  fps_kernel<512, 512, 2><<<dim3(8), dim3(256), 0, stream>>>(p2, p3);
  g_kernel<64, 128><<<dim3(8 * 512 * 128 / 256), dim3(256), 0, stream>>>(x2, p2, w31, g3, 8 * 512);
  sa_kernel<512, 128, 128, 8><<<dim3(64, 8), dim3(256), 0, stream>>>(
      p2, g3, p3, w32, b31, w31 + 64 * 128, b32, 1.0f, 512, x3);
  // ---------------- outputs 1 & 2 ----------------
  tail_kernel<<<dim3(48), dim3(256), 0, stream>>>(p3, (float*)d_out);
}

// Round 6
// 2435.765 us; speedup vs baseline: 1.2552x; 1.2552x over previous
//
#include <hip/hip_runtime.h>
#include <hip/hip_bf16.h>
#include <float.h>

typedef unsigned long long u64;

// ---------- exact-rounding helpers (match numpy fp32, no FMA contraction) ----------
static __device__ __forceinline__ float d2_rn(float ax, float ay, float az,
                                              float bx, float by, float bz) {
  float dx = __fsub_rn(ax, bx), dy = __fsub_rn(ay, by), dz = __fsub_rn(az, bz);
  return __fadd_rn(__fadd_rn(__fmul_rn(dx, dx), __fmul_rn(dy, dy)), __fmul_rn(dz, dz));
}

// merge two descending-sorted top-2 lists of packed keys -> top-2 in (a1,a2)
static __device__ __forceinline__ void merge2(u64& a1, u64& a2, u64 b1, u64 b2) {
  bool agt = a1 > b1;
  u64 m1 = agt ? a1 : b1;
  u64 lo = agt ? b1 : a1;
  u64 cs = agt ? a2 : b2;
  a1 = m1;
  a2 = lo > cs ? lo : cs;
}

static __device__ __forceinline__ u64 pack_key(float v, int i) {
  // nonneg float bits are monotone as uint; ~i gives first-index tie-break under max.
  // Real keys are always > 0 (low word ~i != 0 for i < 2^31), so 0 acts as -inf.
  if (v < 0.f) return 0ull;
  return ((u64)__float_as_uint(v) << 32) | (unsigned)(~i);
}

// DPP cross-lane move of a u64 (two 32-bit halves). bound_ctrl=1 -> invalid lanes read 0.
template<int CTRL>
static __device__ __forceinline__ u64 dpp_u64(u64 x) {
  unsigned lo = (unsigned)__builtin_amdgcn_update_dpp(0, (int)(unsigned)x, CTRL, 0xF, 0xF, true);
  unsigned hi = (unsigned)__builtin_amdgcn_update_dpp(0, (int)(unsigned)(x >> 32), CTRL, 0xF, 0xF, true);
  return ((u64)hi << 32) | lo;
}

template<int CTRL>
static __device__ __forceinline__ void merge_dpp(u64& a1, u64& a2) {
  u64 b1 = dpp_u64<CTRL>(a1);
  u64 b2 = dpp_u64<CTRL>(a2);
  merge2(a1, a2, b1, b2);
}

// Full-wave top-2 reduce at VALU latency; exact result lands in LANE 63.
static __device__ __forceinline__ void wave_top2_dpp(u64& a1, u64& a2) {
  merge_dpp<0xB1>(a1, a2);    // xor 1
  merge_dpp<0x4E>(a1, a2);    // xor 2
  merge_dpp<0x141>(a1, a2);   // row_half_mirror: xor 4
  merge_dpp<0x140>(a1, a2);   // row_mirror: xor 8
  merge_dpp<0x142>(a1, a2);   // row_bcast15
  merge_dpp<0x143>(a1, a2);   // row_bcast31; lane63 = full wave
}

// ---------------- FPS: 1 barrier/step, DPP top-2 argmax, top-2 speculation ----------------
// __launch_bounds__(512, 2): 8 waves resident = 2/EU -> 256-VGPR budget, so the
// allocator keeps md/px/py/pz in VGPRs instead of rematerializing ds_reads
// (round-5 finding: default budget (VGPR=40) turned the update loop into ~192
// wave-level ds_read_b32 per CU per round — the dominant cost).
template<int N, int M, int NPT, int T>
static __device__ void fps_body(const float* __restrict__ P, float* __restrict__ O,
                                char* smem) {
  constexpr int W = T / 64;
  static_assert(N == T * NPT, "layout");
  float* xs = (float*)smem;
  float* ys = xs + N;
  float* zs = ys + N;
  uint4* slots = (uint4*)(zs + N);   // [2][W]
  const int tid = threadIdx.x;
  const int lane = tid & 63, wv = tid >> 6;

  for (int j = tid; j < N; j += T) {
    xs[j] = P[3 * j]; ys[j] = P[3 * j + 1]; zs[j] = P[3 * j + 2];
  }
  __syncthreads();

  const float c0x = xs[0], c0y = ys[0], c0z = zs[0];
  if (tid == 0) { O[0] = c0x; O[1] = c0y; O[2] = c0z; }

  float md[NPT], px[NPT], py[NPT], pz[NPT];
  float v1 = -1.f, v2 = -1.f; int i1 = 0, i2 = 0;
  #pragma unroll
  for (int k = 0; k < NPT; ++k) {
    int j = tid + k * T;  // ascending j -> '>' keeps first index on ties
    px[k] = xs[j]; py[k] = ys[j]; pz[k] = zs[j];
    float m = d2_rn(px[k], py[k], pz[k], c0x, c0y, c0z);
    md[k] = m;
    if (m > v2) { if (m > v1) { v2=v1; i2=i1; v1=m; i1=j; } else { v2=m; i2=j; } }
  }

  u64 a1 = pack_key(v1, i1), a2 = pack_key(v2, i2);
  wave_top2_dpp(a1, a2);
  if (lane == 63)
    slots[wv] = make_uint4((unsigned)a1, (unsigned)(a1 >> 32),
                           (unsigned)a2, (unsigned)(a2 >> 32));

  int t = 1, phase = 0;
  while (t < M) {
    __syncthreads();
    // ---- cross-wave merge: lane reads slot[lane&(W-1)]; 3 DPP levels -> global top-2
    uint4 s = slots[phase * W + (lane & (W - 1))];
    a1 = ((u64)s.y << 32) | s.x;
    a2 = ((u64)s.w << 32) | s.z;
    merge_dpp<0xB1>(a1, a2);   // xor 1
    merge_dpp<0x4E>(a1, a2);   // xor 2
    merge_dpp<0x141>(a1, a2);  // xor 4 (8 slots fully merged, uniform everywhere)

    const int j1 = (int)(~(unsigned)a1);
    const float c1x = xs[j1], c1y = ys[j1], c1z = zs[j1];
    const float v2f = __uint_as_float((unsigned)(a2 >> 32));

    bool hit = false;
    float c2x = 0.f, c2y = 0.f, c2z = 0.f;
    if (t + 1 < M && v2f > 0.f) {
      int j2 = (int)(~(unsigned)a2);
      c2x = xs[j2]; c2y = ys[j2]; c2z = zs[j2];
      float dd = d2_rn(c2x, c2y, c2z, c1x, c1y, c1z);
      hit = (dd >= v2f);   // then md'[j2]=v2 stays the exact (val,first-idx) max
    }

    if (tid == 0) {
      O[3 * t] = c1x; O[3 * t + 1] = c1y; O[3 * t + 2] = c1z;
      if (hit) { O[3 * t + 3] = c2x; O[3 * t + 4] = c2y; O[3 * t + 5] = c2z; }
    }

    v1 = -1.f; v2 = -1.f; i1 = 0; i2 = 0;
    if (hit) {
      #pragma unroll
      for (int k = 0; k < NPT; ++k) {
        float m = md[k];
        m = fminf(m, d2_rn(px[k], py[k], pz[k], c1x, c1y, c1z));
        m = fminf(m, d2_rn(px[k], py[k], pz[k], c2x, c2y, c2z));
        md[k] = m;
        int j = tid + k * T;
        if (m > v2) { if (m > v1) { v2=v1; i2=i1; v1=m; i1=j; } else { v2=m; i2=j; } }
      }
    } else {
      #pragma unroll
      for (int k = 0; k < NPT; ++k) {
        float m = fminf(md[k], d2_rn(px[k], py[k], pz[k], c1x, c1y, c1z));
        md[k] = m;
        int j = tid + k * T;
        if (m > v2) { if (m > v1) { v2=v1; i2=i1; v1=m; i1=j; } else { v2=m; i2=j; } }
      }
    }

    a1 = pack_key(v1, i1); a2 = pack_key(v2, i2);
    wave_top2_dpp(a1, a2);
    if (lane == 63)
      slots[(phase ^ 1) * W + wv] = make_uint4((unsigned)a1, (unsigned)(a1 >> 32),
                                               (unsigned)a2, (unsigned)(a2 >> 32));
    phase ^= 1;
    t += hit ? 2 : 1;
  }
}

template<int N, int M, int NPT>
__global__ __launch_bounds__(512, 2) void fps_kernel(const float* __restrict__ pos,
                                                     float* __restrict__ out) {
  __shared__ __align__(16) char smem[3 * N * 4 + 2 * 8 * 16];
  fps_body<N, M, NPT, 512>(pos + (size_t)blockIdx.x * N * 3,
                           out + (size_t)blockIdx.x * M * 3, smem);
}

// ------------- per-source g[j] = x_j @ W1x + pos_j @ W1p  (tiny GEMM) -------------
template<int C, int H>
__global__ void g_kernel(const float* __restrict__ x, const float* __restrict__ pos,
                         const float* __restrict__ W, float* __restrict__ g, int rows) {
  int idx = blockIdx.x * 256 + threadIdx.x;
  if (idx >= rows * H) return;
  int row = idx / H, h = idx - row * H;
  const float* xr = x + (size_t)row * C;
  const float* pr = pos + (size_t)row * 3;
  float acc = 0.f;
  for (int c = 0; c < C; ++c) acc = fmaf(xr[c], W[c * H + h], acc);
  #pragma unroll
  for (int c = 0; c < 3; ++c) acc = fmaf(pr[c], W[(C + c) * H + h], acc);
  g[idx] = acc;
}

// ---------------- SA layer: ball-query top-64 + MLP + max aggregation ----------------
template<int N, int H, int C, int QB>
__global__ __launch_bounds__(256) void sa_kernel(
    const float* __restrict__ src,   // [B,N,3]
    const float* __restrict__ g,     // [B,N,H]
    const float* __restrict__ qpos,  // [B,M,3]
    const float* __restrict__ W2,    // [H,C]
    const float* __restrict__ b1v,   // [H]
    const float* __restrict__ W1p,   // rows C..C+2 of W1, i.e. [3,H]
    const float* __restrict__ b2v,   // [C]
    float r2, int M,
    float* __restrict__ out)         // [B,M,C]
{
  constexpr int TPS = C / 2;       // threads per subgroup (2 channels each)
  constexpr int SG  = 256 / TPS;   // subgroups = 512 / C
  constexpr int JT  = SG * 4;      // neighbors per tile
  constexpr int STRIDE = JT + 4;
  const int tid = threadIdx.x;
  const int b = blockIdx.y;
  const int sgi = tid / TPS;
  const int c2 = 2 * (tid - sgi * TPS);

  __shared__ __align__(16) __hip_bfloat16 sW2h[H * C];
  __shared__ float sD2[N];
  __shared__ float sT[H];
  __shared__ __align__(16) float sHj[STRIDE * H];
  __shared__ float sScr[512];   // aliased scratch: hist | candidates | final reduce
  __shared__ int   sNbr[64];
  __shared__ int   sWS[4];
  __shared__ int   sCnt, sNn, sNc, sBin, sBefore;
  __shared__ float sTauV; __shared__ int sTauI;

  int*   sHist  = (int*)sScr;          // [0,256)
  float* sCand  = sScr + 256;          // [256,320)
  int*   sCandI = (int*)(sScr + 320);  // [320,384)
  float* sRed   = sScr;                // [0,512) (MLP phase only)

  const float* srcb = src + (size_t)b * N * 3;
  const float* gb   = g   + (size_t)b * N * H;

  for (int e = tid; e < H * C; e += 256) sW2h[e] = __float2bfloat16(W2[e]);

  for (int qi = 0; qi < QB; ++qi) {
    const int i = blockIdx.x * QB + qi;
    const float* qp = qpos + ((size_t)b * M + i) * 3;
    const float qx = qp[0], qy = qp[1], qz = qp[2];
    const float qq = __fadd_rn(__fadd_rn(__fmul_rn(qx, qx), __fmul_rn(qy, qy)),
                               __fmul_rn(qz, qz));
    if (tid < H)
      sT[tid] = fmaf(qx, W1p[tid], fmaf(qy, W1p[H + tid], fmaf(qz, W1p[2 * H + tid], -b1v[tid])));
    if (tid == 0) { sCnt = 0; sNn = 0; sNc = 0; }
    sHist[tid] = 0;
    __syncthreads();

    // ---- pass 1: d2 (reference formula, exact rounding) + in-radius count ----
    int lc = 0;
    for (int j = tid; j < N; j += 256) {
      float sx = srcb[3 * j], sy = srcb[3 * j + 1], sz = srcb[3 * j + 2];
      float ss  = __fadd_rn(__fadd_rn(__fmul_rn(sx, sx), __fmul_rn(sy, sy)), __fmul_rn(sz, sz));
      float dot = __fadd_rn(__fadd_rn(__fmul_rn(qx, sx), __fmul_rn(qy, sy)), __fmul_rn(qz, sz));
      float d2  = __fsub_rn(__fadd_rn(qq, ss), __fmul_rn(2.0f, dot));
      sD2[j] = d2;
      lc += (d2 <= r2) ? 1 : 0;
    }
    #pragma unroll
    for (int off = 32; off > 0; off >>= 1) lc += __shfl_xor(lc, off, 64);
    if ((tid & 63) == 0) atomicAdd(&sCnt, lc);
    __syncthreads();
    const int cnt = sCnt;

    // ---- exact rank-64 threshold (lexicographic (d2, idx), matches lax.top_k) ----
    float tauv; int taui;
    if (cnt <= 64) {
      tauv = r2; taui = 0x7fffffff;
    } else {
      const float scale = 256.0f / r2;
      for (int j = tid; j < N; j += 256) {
        float d2 = sD2[j];
        if (d2 <= r2) {
          int bin = (int)(d2 * scale);
          bin = bin < 0 ? 0 : (bin > 255 ? 255 : bin);
          atomicAdd(&sHist[bin], 1);
        }
      }
      __syncthreads();
      int cbin = sHist[tid];
      int lane = tid & 63, wvi = tid >> 6;
      int v = cbin;
      #pragma unroll
      for (int off = 1; off < 64; off <<= 1) {
        int o = __shfl_up(v, off, 64);
        if (lane >= off) v += o;
      }
      if (lane == 63) sWS[wvi] = v;
      __syncthreads();
      int wadd = 0;
      for (int w = 0; w < wvi; ++w) wadd += sWS[w];
      int incl = v + wadd, excl = incl - cbin;
      if (excl < 64 && incl >= 64) { sBin = tid; sBefore = excl; }
      __syncthreads();
      const int bstar = sBin;
      const int kneed = 64 - sBefore;
      for (int j = tid; j < N; j += 256) {
        float d2 = sD2[j];
        if (d2 <= r2) {
          int bin = (int)(d2 * scale);
          bin = bin < 0 ? 0 : (bin > 255 ? 255 : bin);
          if (bin == bstar) {
            int p = atomicAdd(&sNc, 1);
            if (p < 64) { sCand[p] = d2; sCandI[p] = j; }
          }
        }
      }
      __syncthreads();
      if (tid == 0) {
        int nc = sNc < 64 ? sNc : 64;
        for (int a = 1; a < nc; ++a) {
          float dv = sCand[a]; int di = sCandI[a];
          int p = a - 1;
          while (p >= 0 && (sCand[p] > dv || (sCand[p] == dv && sCandI[p] > di))) {
            sCand[p + 1] = sCand[p]; sCandI[p + 1] = sCandI[p]; --p;
          }
          sCand[p + 1] = dv; sCandI[p + 1] = di;
        }
        int kk = (kneed < nc ? kneed : nc) - 1; if (kk < 0) kk = 0;
        sTauV = sCand[kk]; sTauI = sCandI[kk];
      }
      __syncthreads();
      tauv = sTauV; taui = sTauI;
    }

    // ---- compact neighbor list (set membership only; order irrelevant for max) ----
    for (int j = tid; j < N; j += 256) {
      float d2 = sD2[j];
      if (d2 < tauv || (d2 == tauv && j <= taui)) {
        int p = atomicAdd(&sNn, 1);
        if (p < 64) sNbr[p] = j;
      }
    }
    __syncthreads();
    const int nn = sNn < 64 ? sNn : 64;

    // ---- MLP: h = ReLU(g[j]-t[i]);  out_c = max_j (h @ W2)_c + b2_c ----
    float m0 = -FLT_MAX, m1 = -FLT_MAX;
    for (int t0 = 0; t0 < nn; t0 += JT) {
      int jt = nn - t0; if (jt > JT) jt = JT;
      __syncthreads();
      for (int e = tid; e < JT * H; e += 256) {
        int jj = e / H, h = e - jj * H;
        float hv = 0.f;
        if (jj < jt) {
          int j = sNbr[t0 + jj];
          hv = gb[(size_t)j * H + h] - sT[h];
          hv = hv > 0.f ? hv : 0.f;
        }
        sHj[h * STRIDE + jj] = hv;
      }
      __syncthreads();
      float a0 = 0, a1 = 0, a2 = 0, a3 = 0, c0 = 0, c1 = 0, c2a = 0, c3 = 0;
      const int jbase = sgi * 4;
      for (int h = 0; h < H; ++h) {
        float4 hv = *reinterpret_cast<const float4*>(&sHj[h * STRIDE + jbase]);
        __hip_bfloat162 wp = *reinterpret_cast<const __hip_bfloat162*>(&sW2h[h * C + c2]);
        float wx = __bfloat162float(wp.x), wy = __bfloat162float(wp.y);
        a0 = fmaf(hv.x, wx, a0); a1 = fmaf(hv.y, wx, a1);
        a2 = fmaf(hv.z, wx, a2); a3 = fmaf(hv.w, wx, a3);
        c0 = fmaf(hv.x, wy, c0); c1 = fmaf(hv.y, wy, c1);
        c2a = fmaf(hv.z, wy, c2a); c3 = fmaf(hv.w, wy, c3);
      }
      if (jbase + 0 < jt) { m0 = fmaxf(m0, a0); m1 = fmaxf(m1, c0); }
      if (jbase + 1 < jt) { m0 = fmaxf(m0, a1); m1 = fmaxf(m1, c1); }
      if (jbase + 2 < jt) { m0 = fmaxf(m0, a2); m1 = fmaxf(m1, c2a); }
      if (jbase + 3 < jt) { m0 = fmaxf(m0, a3); m1 = fmaxf(m1, c3); }
    }
    __syncthreads();
    sRed[sgi * C + c2]     = m0;
    sRed[sgi * C + c2 + 1] = m1;
    __syncthreads();
    if (tid < TPS) {
      int c = 2 * tid;
      float M0 = sRed[c], M1 = sRed[c + 1];
      #pragma unroll
      for (int s2 = 1; s2 < SG; ++s2) {
        M0 = fmaxf(M0, sRed[s2 * C + c]);
        M1 = fmaxf(M1, sRed[s2 * C + c + 1]);
      }
      float o0 = nn > 0 ? M0 + b2v[c]     : 0.f;
      float o1 = nn > 0 ? M1 + b2v[c + 1] : 0.f;
      float* orow = out + (((size_t)b * M) + i) * C;
      orow[c] = o0; orow[c + 1] = o1;
    }
    __syncthreads();
  }
}

// ---------------- tail: copy p3 and synthesize batch ids into d_out ----------------
__global__ void tail_kernel(const float* __restrict__ p3, float* __restrict__ d_out) {
  int i = blockIdx.x * 256 + threadIdx.x;
  if (i < 8 * 512 * 3) d_out[524288 + i] = p3[i];
  if (i < 8 * 512)     d_out[536576 + i] = (float)(i >> 9);
}

extern "C" void kernel_launch(void* const* d_in, const int* in_sizes, int n_in,
                              void* d_out, int out_size, void* d_ws, size_t ws_size,
                              hipStream_t stream) {
  (void)in_sizes; (void)n_in; (void)out_size; (void)ws_size;
  const float* pos = (const float*)d_in[0];
  const float* w11 = (const float*)d_in[2];
  const float* b11 = (const float*)d_in[3];
  const float* w12 = (const float*)d_in[4];
  const float* b12 = (const float*)d_in[5];
  const float* w21 = (const float*)d_in[6];
  const float* b21 = (const float*)d_in[7];
  const float* w22 = (const float*)d_in[8];
  const float* b22 = (const float*)d_in[9];
  const float* w31 = (const float*)d_in[10];
  const float* b31 = (const float*)d_in[11];
  const float* w32 = (const float*)d_in[12];
  const float* b32 = (const float*)d_in[13];

  float* ws = (float*)d_ws;
  float* p1 = ws; ws += 8 * 2048 * 3;
  float* p2 = ws; ws += 8 * 512 * 3;
  float* p3 = ws; ws += 8 * 512 * 3;
  float* g1 = ws; ws += 8 * 4096 * 32;
  float* x1 = ws; ws += 8 * 2048 * 32;
  float* g2 = ws; ws += 8 * 2048 * 64;
  float* x2 = ws; ws += 8 * 512 * 64;
  float* g3 = ws; ws += 8 * 512 * 128;
  float* x3 = (float*)d_out;

  // ---------------- layer 1 ----------------
  fps_kernel<4096, 2048, 8><<<dim3(8), dim3(512), 0, stream>>>(pos, p1);
  g_kernel<3, 32><<<dim3(8 * 4096 * 32 / 256), dim3(256), 0, stream>>>(pos, pos, w11, g1, 8 * 4096);
  sa_kernel<4096, 32, 32, 8><<<dim3(2048 / 8, 8), dim3(256), 0, stream>>>(
      pos, g1, p1, w12, b11, w11 + 3 * 32, b12, 0.04f, 2048, x1);
  // ---------------- layer 2 ----------------
  fps_kernel<2048, 512, 4><<<dim3(8), dim3(512), 0, stream>>>(p1, p2);
  g_kernel<32, 64><<<dim3(8 * 2048 * 64 / 256), dim3(256), 0, stream>>>(x1, p1, w21, g2, 8 * 2048);
  sa_kernel<2048, 64, 64, 8><<<dim3(512 / 8, 8), dim3(256), 0, stream>>>(
      p1, g2, p2, w22, b21, w21 + 32 * 64, b22, 0.16f, 512, x2);
  // ---------------- layer 3 ----------------
  fps_kernel<512, 512, 1><<<dim3(8), dim3(512), 0, stream>>>(p2, p3);
  g_kernel<64, 128><<<dim3(8 * 512 * 128 / 256), dim3(256), 0, stream>>>(x2, p2, w31, g3, 8 * 512);
  sa_kernel<512, 128, 128, 8><<<dim3(64, 8), dim3(256), 0, stream>>>(
      p2, g3, p3, w32, b31, w31 + 64 * 128, b32, 1.0f, 512, x3);
  // ---------------- outputs 1 & 2 ----------------
  tail_kernel<<<dim3(48), dim3(256), 0, stream>>>(p3, (float*)d_out);
}

// Round 7
// 2185.206 us; speedup vs baseline: 1.3992x; 1.1147x over previous
//
#include <hip/hip_runtime.h>
#include <hip/hip_bf16.h>
#include <float.h>

typedef unsigned long long u64;

// ---------- exact-rounding helpers (match numpy fp32, no FMA contraction) ----------
static __device__ __forceinline__ float d2_rn(float ax, float ay, float az,
                                              float bx, float by, float bz) {
  float dx = __fsub_rn(ax, bx), dy = __fsub_rn(ay, by), dz = __fsub_rn(az, bz);
  return __fadd_rn(__fadd_rn(__fmul_rn(dx, dx), __fmul_rn(dy, dy)), __fmul_rn(dz, dz));
}

// merge two descending-sorted top-2 lists of packed keys -> top-2 in (a1,a2)
static __device__ __forceinline__ void merge2(u64& a1, u64& a2, u64 b1, u64 b2) {
  bool agt = a1 > b1;
  u64 m1 = agt ? a1 : b1;
  u64 lo = agt ? b1 : a1;
  u64 cs = agt ? a2 : b2;
  a1 = m1;
  a2 = lo > cs ? lo : cs;
}

static __device__ __forceinline__ u64 pack_key(float v, int i) {
  // nonneg float bits are monotone as uint; ~i gives first-index tie-break under max.
  if (v < 0.f) return 0ull;
  return ((u64)__float_as_uint(v) << 32) | (unsigned)(~i);
}

// DPP cross-lane move of a u64 (two 32-bit halves). bound_ctrl=1 -> invalid lanes read 0.
template<int CTRL>
static __device__ __forceinline__ u64 dpp_u64(u64 x) {
  unsigned lo = (unsigned)__builtin_amdgcn_update_dpp(0, (int)(unsigned)x, CTRL, 0xF, 0xF, true);
  unsigned hi = (unsigned)__builtin_amdgcn_update_dpp(0, (int)(unsigned)(x >> 32), CTRL, 0xF, 0xF, true);
  return ((u64)hi << 32) | lo;
}

template<int CTRL>
static __device__ __forceinline__ void merge_dpp(u64& a1, u64& a2) {
  u64 b1 = dpp_u64<CTRL>(a1);
  u64 b2 = dpp_u64<CTRL>(a2);
  merge2(a1, a2, b1, b2);
}

// Full-wave top-2 reduce at VALU latency; exact result lands in LANE 63.
static __device__ __forceinline__ void wave_top2_dpp(u64& a1, u64& a2) {
  merge_dpp<0xB1>(a1, a2);    // xor 1
  merge_dpp<0x4E>(a1, a2);    // xor 2
  merge_dpp<0x141>(a1, a2);   // row_half_mirror: xor 4
  merge_dpp<0x140>(a1, a2);   // row_mirror: xor 8
  merge_dpp<0x142>(a1, a2);   // row_bcast15
  merge_dpp<0x143>(a1, a2);   // row_bcast31; lane63 = full wave
}

// ---------------- FPS: 1 barrier/step, DPP top-2 argmax, top-2 speculation ----------------
template<int N, int M, int NPT, int T>
static __device__ void fps_body(const float* __restrict__ P, float* __restrict__ O,
                                char* smem) {
  constexpr int W = T / 64;
  static_assert(N == T * NPT, "layout");
  float* xs = (float*)smem;
  float* ys = xs + N;
  float* zs = ys + N;
  uint4* slots = (uint4*)(zs + N);   // [2][W]
  const int tid = threadIdx.x;
  const int lane = tid & 63, wv = tid >> 6;

  for (int j = tid; j < N; j += T) {
    xs[j] = P[3 * j]; ys[j] = P[3 * j + 1]; zs[j] = P[3 * j + 2];
  }
  __syncthreads();

  const float c0x = xs[0], c0y = ys[0], c0z = zs[0];
  if (tid == 0) { O[0] = c0x; O[1] = c0y; O[2] = c0z; }

  float md[NPT], px[NPT], py[NPT], pz[NPT];
  float v1 = -1.f, v2 = -1.f; int i1 = 0, i2 = 0;
  #pragma unroll
  for (int k = 0; k < NPT; ++k) {
    int j = tid + k * T;  // ascending j -> '>' keeps first index on ties
    px[k] = xs[j]; py[k] = ys[j]; pz[k] = zs[j];
    float m = d2_rn(px[k], py[k], pz[k], c0x, c0y, c0z);
    md[k] = m;
    if (m > v2) { if (m > v1) { v2=v1; i2=i1; v1=m; i1=j; } else { v2=m; i2=j; } }
  }

  u64 a1 = pack_key(v1, i1), a2 = pack_key(v2, i2);
  wave_top2_dpp(a1, a2);
  if (lane == 63)
    slots[wv] = make_uint4((unsigned)a1, (unsigned)(a1 >> 32),
                           (unsigned)a2, (unsigned)(a2 >> 32));

  int t = 1, phase = 0;
  while (t < M) {
    __syncthreads();
    // ---- cross-wave merge: lane reads slot[lane&(W-1)]; 3 DPP levels -> global top-2
    uint4 s = slots[phase * W + (lane & (W - 1))];
    a1 = ((u64)s.y << 32) | s.x;
    a2 = ((u64)s.w << 32) | s.z;
    merge_dpp<0xB1>(a1, a2);   // xor 1
    merge_dpp<0x4E>(a1, a2);   // xor 2
    merge_dpp<0x141>(a1, a2);  // xor 4 (8 slots fully merged, uniform everywhere)

    const int j1 = (int)(~(unsigned)a1);
    const float c1x = xs[j1], c1y = ys[j1], c1z = zs[j1];
    const float v2f = __uint_as_float((unsigned)(a2 >> 32));

    bool hit = false;
    float c2x = 0.f, c2y = 0.f, c2z = 0.f;
    if (t + 1 < M && v2f > 0.f) {
      int j2 = (int)(~(unsigned)a2);
      c2x = xs[j2]; c2y = ys[j2]; c2z = zs[j2];
      float dd = d2_rn(c2x, c2y, c2z, c1x, c1y, c1z);
      hit = (dd >= v2f);   // then md'[j2]=v2 stays the exact (val,first-idx) max
    }

    if (tid == 0) {
      O[3 * t] = c1x; O[3 * t + 1] = c1y; O[3 * t + 2] = c1z;
      if (hit) { O[3 * t + 3] = c2x; O[3 * t + 4] = c2y; O[3 * t + 5] = c2z; }
    }

    v1 = -1.f; v2 = -1.f; i1 = 0; i2 = 0;
    if (hit) {
      #pragma unroll
      for (int k = 0; k < NPT; ++k) {
        float m = md[k];
        m = fminf(m, d2_rn(px[k], py[k], pz[k], c1x, c1y, c1z));
        m = fminf(m, d2_rn(px[k], py[k], pz[k], c2x, c2y, c2z));
        md[k] = m;
        int j = tid + k * T;
        if (m > v2) { if (m > v1) { v2=v1; i2=i1; v1=m; i1=j; } else { v2=m; i2=j; } }
      }
    } else {
      #pragma unroll
      for (int k = 0; k < NPT; ++k) {
        float m = fminf(md[k], d2_rn(px[k], py[k], pz[k], c1x, c1y, c1z));
        md[k] = m;
        int j = tid + k * T;
        if (m > v2) { if (m > v1) { v2=v1; i2=i1; v1=m; i1=j; } else { v2=m; i2=j; } }
      }
    }

    a1 = pack_key(v1, i1); a2 = pack_key(v2, i2);
    wave_top2_dpp(a1, a2);
    if (lane == 63)
      slots[(phase ^ 1) * W + wv] = make_uint4((unsigned)a1, (unsigned)(a1 >> 32),
                                               (unsigned)a2, (unsigned)(a2 >> 32));
    phase ^= 1;
    t += hit ? 2 : 1;
  }
}

template<int N, int M, int NPT>
__global__ __launch_bounds__(512, 2) void fps_kernel(const float* __restrict__ pos,
                                                     float* __restrict__ out) {
  __shared__ __align__(16) char smem[3 * N * 4 + 2 * 8 * 16];
  fps_body<N, M, NPT, 512>(pos + (size_t)blockIdx.x * N * 3,
                           out + (size_t)blockIdx.x * M * 3, smem);
}

// ------------- per-source g[j] = x_j @ W1x + pos_j @ W1p  (tiny GEMM) -------------
template<int C, int H>
__global__ void g_kernel(const float* __restrict__ x, const float* __restrict__ pos,
                         const float* __restrict__ W, float* __restrict__ g, int rows) {
  int idx = blockIdx.x * 256 + threadIdx.x;
  if (idx >= rows * H) return;
  int row = idx / H, h = idx - row * H;
  const float* xr = x + (size_t)row * C;
  const float* pr = pos + (size_t)row * 3;
  float acc = 0.f;
  for (int c = 0; c < C; ++c) acc = fmaf(xr[c], W[c * H + h], acc);
  #pragma unroll
  for (int c = 0; c < 3; ++c) acc = fmaf(pr[c], W[(C + c) * H + h], acc);
  g[idx] = acc;
}

// ---------------- SA layer body (templated on thread count T) ----------------
template<int N, int H, int C, int T>
constexpr int sa_smem_bytes() {
  constexpr int TPS = C / 2, SG = T / TPS, JT = SG * 4, STRIDE = JT + 4;
  constexpr int SCR = (SG * C > 512) ? SG * C : 512;
  return H * C * 2 + N * 4 + H * 4 + STRIDE * H * 4 + SCR * 4 + 64 * 4 + 8 * 4 + 8 * 4;
}

template<int N, int H, int C, int QB, int T>
static __device__ void sa_body(const float* __restrict__ srcb,  // [N,3]
                               const float* __restrict__ gb,    // [N,H]
                               const float* __restrict__ qposb, // [M,3]
                               const float* __restrict__ W2, const float* __restrict__ b1v,
                               const float* __restrict__ W1p, const float* __restrict__ b2v,
                               float r2, int M, float* __restrict__ outb, int qtile,
                               char* smem) {
  constexpr int TPS = C / 2;
  constexpr int SG  = T / TPS;
  constexpr int JT  = SG * 4;
  constexpr int STRIDE = JT + 4;
  constexpr int SCR = (SG * C > 512) ? SG * C : 512;
  const int tid = threadIdx.x;
  const int sgi = tid / TPS;
  const int c2 = 2 * (tid - sgi * TPS);

  __hip_bfloat16* sW2h = (__hip_bfloat16*)smem;          // H*C*2
  float* sD2  = (float*)(smem + H * C * 2);              // N
  float* sT   = sD2 + N;                                 // H
  float* sHj  = sT + H;                                  // STRIDE*H (16B aligned)
  float* sScr = sHj + STRIDE * H;                        // SCR
  int*   sNbr = (int*)(sScr + SCR);                      // 64
  int*   sWS  = sNbr + 64;                               // 8
  int*   sIv  = sWS + 8;   // [0]=Cnt [1]=Nn [2]=Nc [3]=Bin [4]=Before [5]=TauI
  float* sFv  = (float*)(sIv + 6);  // [0]=TauV

  int*   sHist  = (int*)sScr;
  float* sCand  = sScr + 256;
  int*   sCandI = (int*)(sScr + 320);
  float* sRed   = sScr;

  for (int e = tid; e < H * C; e += T) sW2h[e] = __float2bfloat16(W2[e]);

  for (int qi = 0; qi < QB; ++qi) {
    const int i = qtile * QB + qi;
    const float* qp = qposb + (size_t)i * 3;
    const float qx = qp[0], qy = qp[1], qz = qp[2];
    const float qq = __fadd_rn(__fadd_rn(__fmul_rn(qx, qx), __fmul_rn(qy, qy)),
                               __fmul_rn(qz, qz));
    if (tid < H)
      sT[tid] = fmaf(qx, W1p[tid], fmaf(qy, W1p[H + tid], fmaf(qz, W1p[2 * H + tid], -b1v[tid])));
    if (tid == 0) { sIv[0] = 0; sIv[1] = 0; sIv[2] = 0; }
    if (tid < 256) sHist[tid] = 0;
    __syncthreads();

    // ---- pass 1: d2 (reference formula, exact rounding) + in-radius count ----
    int lc = 0;
    for (int j = tid; j < N; j += T) {
      float sx = srcb[3 * j], sy = srcb[3 * j + 1], sz = srcb[3 * j + 2];
      float ss  = __fadd_rn(__fadd_rn(__fmul_rn(sx, sx), __fmul_rn(sy, sy)), __fmul_rn(sz, sz));
      float dot = __fadd_rn(__fadd_rn(__fmul_rn(qx, sx), __fmul_rn(qy, sy)), __fmul_rn(qz, sz));
      float d2  = __fsub_rn(__fadd_rn(qq, ss), __fmul_rn(2.0f, dot));
      sD2[j] = d2;
      lc += (d2 <= r2) ? 1 : 0;
    }
    #pragma unroll
    for (int off = 32; off > 0; off >>= 1) lc += __shfl_xor(lc, off, 64);
    if ((tid & 63) == 0) atomicAdd(&sIv[0], lc);
    __syncthreads();
    const int cnt = sIv[0];

    // ---- exact rank-64 threshold (lexicographic (d2, idx), matches lax.top_k) ----
    float tauv; int taui;
    if (cnt <= 64) {
      tauv = r2; taui = 0x7fffffff;
    } else {
      const float scale = 256.0f / r2;
      for (int j = tid; j < N; j += T) {
        float d2 = sD2[j];
        if (d2 <= r2) {
          int bin = (int)(d2 * scale);
          bin = bin < 0 ? 0 : (bin > 255 ? 255 : bin);
          atomicAdd(&sHist[bin], 1);
        }
      }
      __syncthreads();
      int cbin = (tid < 256) ? sHist[tid] : 0;
      int lane = tid & 63, wvi = tid >> 6;
      int v = cbin;
      #pragma unroll
      for (int off = 1; off < 64; off <<= 1) {
        int o = __shfl_up(v, off, 64);
        if (lane >= off) v += o;
      }
      if (lane == 63) sWS[wvi] = v;
      __syncthreads();
      int wadd = 0;
      for (int w = 0; w < wvi; ++w) wadd += sWS[w];
      int incl = v + wadd, excl = incl - cbin;
      if (tid < 256 && excl < 64 && incl >= 64) { sIv[3] = tid; sIv[4] = excl; }
      __syncthreads();
      const int bstar = sIv[3];
      const int kneed = 64 - sIv[4];
      for (int j = tid; j < N; j += T) {
        float d2 = sD2[j];
        if (d2 <= r2) {
          int bin = (int)(d2 * scale);
          bin = bin < 0 ? 0 : (bin > 255 ? 255 : bin);
          if (bin == bstar) {
            int p = atomicAdd(&sIv[2], 1);
            if (p < 64) { sCand[p] = d2; sCandI[p] = j; }
          }
        }
      }
      __syncthreads();
      if (tid == 0) {
        int nc = sIv[2] < 64 ? sIv[2] : 64;
        for (int a = 1; a < nc; ++a) {
          float dv = sCand[a]; int di = sCandI[a];
          int p = a - 1;
          while (p >= 0 && (sCand[p] > dv || (sCand[p] == dv && sCandI[p] > di))) {
            sCand[p + 1] = sCand[p]; sCandI[p + 1] = sCandI[p]; --p;
          }
          sCand[p + 1] = dv; sCandI[p + 1] = di;
        }
        int kk = (kneed < nc ? kneed : nc) - 1; if (kk < 0) kk = 0;
        sFv[0] = sCand[kk]; sIv[5] = sCandI[kk];
      }
      __syncthreads();
      tauv = sFv[0]; taui = sIv[5];
    }

    // ---- compact neighbor list (set membership only; order irrelevant for max) ----
    for (int j = tid; j < N; j += T) {
      float d2 = sD2[j];
      if (d2 < tauv || (d2 == tauv && j <= taui)) {
        int p = atomicAdd(&sIv[1], 1);
        if (p < 64) sNbr[p] = j;
      }
    }
    __syncthreads();
    const int nn = sIv[1] < 64 ? sIv[1] : 64;

    // ---- MLP: h = ReLU(g[j]-t[i]);  out_c = max_j (h @ W2)_c + b2_c ----
    float m0 = -FLT_MAX, m1 = -FLT_MAX;
    for (int t0 = 0; t0 < nn; t0 += JT) {
      int jt = nn - t0; if (jt > JT) jt = JT;
      __syncthreads();
      for (int e = tid; e < JT * H; e += T) {
        int jj = e / H, h = e - jj * H;
        float hv = 0.f;
        if (jj < jt) {
          int j = sNbr[t0 + jj];
          hv = gb[(size_t)j * H + h] - sT[h];
          hv = hv > 0.f ? hv : 0.f;
        }
        sHj[h * STRIDE + jj] = hv;
      }
      __syncthreads();
      float a0 = 0, a1 = 0, a2 = 0, a3 = 0, c0 = 0, c1 = 0, c2a = 0, c3 = 0;
      const int jbase = sgi * 4;
      for (int h = 0; h < H; ++h) {
        float4 hv = *reinterpret_cast<const float4*>(&sHj[h * STRIDE + jbase]);
        __hip_bfloat162 wp = *reinterpret_cast<const __hip_bfloat162*>(&sW2h[h * C + c2]);
        float wx = __bfloat162float(wp.x), wy = __bfloat162float(wp.y);
        a0 = fmaf(hv.x, wx, a0); a1 = fmaf(hv.y, wx, a1);
        a2 = fmaf(hv.z, wx, a2); a3 = fmaf(hv.w, wx, a3);
        c0 = fmaf(hv.x, wy, c0); c1 = fmaf(hv.y, wy, c1);
        c2a = fmaf(hv.z, wy, c2a); c3 = fmaf(hv.w, wy, c3);
      }
      if (jbase + 0 < jt) { m0 = fmaxf(m0, a0); m1 = fmaxf(m1, c0); }
      if (jbase + 1 < jt) { m0 = fmaxf(m0, a1); m1 = fmaxf(m1, c1); }
      if (jbase + 2 < jt) { m0 = fmaxf(m0, a2); m1 = fmaxf(m1, c2a); }
      if (jbase + 3 < jt) { m0 = fmaxf(m0, a3); m1 = fmaxf(m1, c3); }
    }
    __syncthreads();
    sRed[sgi * C + c2]     = m0;
    sRed[sgi * C + c2 + 1] = m1;
    __syncthreads();
    if (tid < TPS) {
      int c = 2 * tid;
      float M0 = sRed[c], M1 = sRed[c + 1];
      #pragma unroll
      for (int s2 = 1; s2 < SG; ++s2) {
        M0 = fmaxf(M0, sRed[s2 * C + c]);
        M1 = fmaxf(M1, sRed[s2 * C + c + 1]);
      }
      float o0 = nn > 0 ? M0 + b2v[c]     : 0.f;
      float o1 = nn > 0 ? M1 + b2v[c + 1] : 0.f;
      float* orow = outb + (size_t)i * C;
      orow[c] = o0; orow[c + 1] = o1;
    }
    __syncthreads();
  }
}

template<int N, int H, int C, int QB>
__global__ __launch_bounds__(256) void sa_kernel(
    const float* __restrict__ src, const float* __restrict__ g,
    const float* __restrict__ qpos, const float* __restrict__ W2,
    const float* __restrict__ b1v, const float* __restrict__ W1p,
    const float* __restrict__ b2v, float r2, int M, float* __restrict__ out) {
  __shared__ __align__(16) char smem[sa_smem_bytes<N, H, C, 256>()];
  const int b = blockIdx.y;
  sa_body<N, H, C, QB, 256>(src + (size_t)b * N * 3, g + (size_t)b * N * H,
                            qpos + (size_t)b * M * 3, W2, b1v, W1p, b2v, r2, M,
                            out + (size_t)b * M * C, blockIdx.x, smem);
}

// ------- fused: blocks 0-7 run FPS (next layer's sampling), rest run SA (this layer) -------
template<int NF, int MF, int NPTF, int NS, int HS, int CS, int QB, int SAB>
__global__ __launch_bounds__(512, 2) void fused_kernel(
    const float* __restrict__ fsrc, float* __restrict__ fdst,
    const float* __restrict__ src, const float* __restrict__ g,
    const float* __restrict__ qpos, const float* __restrict__ W2,
    const float* __restrict__ b1v, const float* __restrict__ W1p,
    const float* __restrict__ b2v, float r2, int M, float* __restrict__ out) {
  constexpr int FPS_BYTES = 3 * NF * 4 + 2 * 8 * 16;
  constexpr int SA_BYTES  = sa_smem_bytes<NS, HS, CS, 512>();
  constexpr int SMEM = FPS_BYTES > SA_BYTES ? FPS_BYTES : SA_BYTES;
  __shared__ __align__(16) char smem[SMEM];
  if (blockIdx.x < 8) {
    __builtin_amdgcn_s_setprio(3);  // FPS is the latency-critical serial chain
    fps_body<NF, MF, NPTF, 512>(fsrc + (size_t)blockIdx.x * NF * 3,
                                fdst + (size_t)blockIdx.x * MF * 3, smem);
    return;
  }
  const int bi = blockIdx.x - 8;
  const int qt = bi % SAB;
  const int b  = bi / SAB;
  sa_body<NS, HS, CS, QB, 512>(src + (size_t)b * NS * 3, g + (size_t)b * NS * HS,
                               qpos + (size_t)b * M * 3, W2, b1v, W1p, b2v, r2, M,
                               out + (size_t)b * M * CS, qt, smem);
}

// ---------------- tail: copy p3 and synthesize batch ids into d_out ----------------
__global__ void tail_kernel(const float* __restrict__ p3, float* __restrict__ d_out) {
  int i = blockIdx.x * 256 + threadIdx.x;
  if (i < 8 * 512 * 3) d_out[524288 + i] = p3[i];
  if (i < 8 * 512)     d_out[536576 + i] = (float)(i >> 9);
}

extern "C" void kernel_launch(void* const* d_in, const int* in_sizes, int n_in,
                              void* d_out, int out_size, void* d_ws, size_t ws_size,
                              hipStream_t stream) {
  (void)in_sizes; (void)n_in; (void)out_size; (void)ws_size;
  const float* pos = (const float*)d_in[0];
  const float* w11 = (const float*)d_in[2];
  const float* b11 = (const float*)d_in[3];
  const float* w12 = (const float*)d_in[4];
  const float* b12 = (const float*)d_in[5];
  const float* w21 = (const float*)d_in[6];
  const float* b21 = (const float*)d_in[7];
  const float* w22 = (const float*)d_in[8];
  const float* b22 = (const float*)d_in[9];
  const float* w31 = (const float*)d_in[10];
  const float* b31 = (const float*)d_in[11];
  const float* w32 = (const float*)d_in[12];
  const float* b32 = (const float*)d_in[13];

  float* ws = (float*)d_ws;
  float* p1 = ws; ws += 8 * 2048 * 3;
  float* p2 = ws; ws += 8 * 512 * 3;
  float* p3 = ws; ws += 8 * 512 * 3;
  float* g1 = ws; ws += 8 * 4096 * 32;
  float* x1 = ws; ws += 8 * 2048 * 32;
  float* g2 = ws; ws += 8 * 2048 * 64;
  float* x2 = ws; ws += 8 * 512 * 64;
  float* g3 = ws; ws += 8 * 512 * 128;
  float* x3 = (float*)d_out;

  // layer 1: g1 (tiny, independent), then FPS1 (the long serial chain)
  g_kernel<3, 32><<<dim3(8 * 4096 * 32 / 256), dim3(256), 0, stream>>>(pos, pos, w11, g1, 8 * 4096);
  fps_kernel<4096, 2048, 8><<<dim3(8), dim3(512), 0, stream>>>(pos, p1);

  // fused A: fps2 (p1->p2) overlapped with sa1 (pos,g1,p1 -> x1); SAB = 2048/8 = 256
  fused_kernel<2048, 512, 4, 4096, 32, 32, 8, 256><<<dim3(8 + 8 * 256), dim3(512), 0, stream>>>(
      p1, p2, pos, g1, p1, w12, b11, w11 + 3 * 32, b12, 0.04f, 2048, x1);

  g_kernel<32, 64><<<dim3(8 * 2048 * 64 / 256), dim3(256), 0, stream>>>(x1, p1, w21, g2, 8 * 2048);

  // fused B: fps3 (p2->p3) overlapped with sa2 (p1,g2,p2 -> x2); SAB = 512/8 = 64
  fused_kernel<512, 512, 1, 2048, 64, 64, 8, 64><<<dim3(8 + 8 * 64), dim3(512), 0, stream>>>(
      p2, p3, p1, g2, p2, w22, b21, w21 + 32 * 64, b22, 0.16f, 512, x2);

  g_kernel<64, 128><<<dim3(8 * 512 * 128 / 256), dim3(256), 0, stream>>>(x2, p2, w31, g3, 8 * 512);

  sa_kernel<512, 128, 128, 8><<<dim3(64, 8), dim3(256), 0, stream>>>(
      p2, g3, p3, w32, b31, w31 + 64 * 128, b32, 1.0f, 512, x3);

  tail_kernel<<<dim3(48), dim3(256), 0, stream>>>(p3, (float*)d_out);
}